// Round 6
// baseline (166.762 us; speedup 1.0000x reference)
//
#include <hip/hip_runtime.h>

typedef __attribute__((ext_vector_type(8))) short  short8;
typedef __attribute__((ext_vector_type(4))) float  f32x4;

#define CIN 32
#define COUT 32
#define DD 32
#define HH 48
#define WW 48
#define NTAP 27
#define SPATIAL (DD*HH*WW)          // 73728

// ---- ws layout (bytes) ----
#define BP2_ELEMS (27*6*64*8)                       // conv B-pack: 82944
#define OFF_WPK   ((size_t)BP2_ELEMS*2)             // 165888
#define WPK_ELEMS (27*2*64*8)                       // einsum B-pack: 27648
#define OFF_XT    (OFF_WPK + (size_t)WPK_ELEMS*2)   // 221184 (16B aligned)
// xT bf16: 4,718,592 B -> total ~4.94 MB

__device__ __forceinline__ unsigned short f2bf(float f) {
    union { float f; unsigned u; } v; v.f = f;
    unsigned r = v.u + 0x7FFFu + ((v.u >> 16) & 1u);   // RNE
    return (unsigned short)(r >> 16);
}
__device__ __forceinline__ float bf2f(unsigned short h) {
    union { unsigned u; float f; } v; v.u = ((unsigned)h) << 16;
    return v.f;
}

// ---------------------------------------------------------------- prep kernels
// conv B-pack, TAP-MAJOR output channels:
//   oc'(n,axis) = ts*48 + (n - 14*ts)*3 + axis, ts = (n>=14)
//   Bp2[((ktap*6 + j)*64 + lane)*8 + e] = bf16(w_off[axis*27+n][kg*8+e][ktap])
__global__ __launch_bounds__(256) void wprep2_kernel(
        const float* __restrict__ w_off, unsigned short* __restrict__ Bp2)
{
    int i = blockIdx.x * 256 + threadIdx.x;
    if (i >= BP2_ELEMS) return;
    int e    = i & 7;
    int lane = (i >> 3) & 63;
    int j    = (i >> 9) % 6;
    int ktap = i / (512 * 6);
    int col = lane & 15, kg = lane >> 4;
    int ocp = j * 16 + col;              // 0..95
    int ts  = ocp >= 48;
    int r   = ocp - 48 * ts;             // 0..47
    int nl  = r / 3, axis = r - 3 * nl;
    int n   = 14 * ts + nl;
    int c   = kg * 8 + e;
    bool valid = ts ? (r < 39) : (r < 42);
    float v = valid ? w_off[((size_t)(axis * 27 + n) * CIN + c) * NTAP + ktap] : 0.f;
    Bp2[i] = f2bf(v);
}

// einsum B-pack: wpk[((n*2+half)*64+lane)*8+e] = bf16(w_def[half*16+col][kg*8+e][n])
__global__ __launch_bounds__(256) void wdefprep_kernel(
        const float* __restrict__ w_def, unsigned short* __restrict__ wpk)
{
    int i = blockIdx.x * 256 + threadIdx.x;
    if (i >= WPK_ELEMS) return;
    int e    = i & 7;
    int lane = (i >> 3) & 63;
    int half = (i >> 9) & 1;
    int n    = i >> 10;
    int kg = lane >> 4, col = lane & 15;
    int c  = kg * 8 + e, oc = half * 16 + col;
    wpk[i] = f2bf(w_def[((size_t)oc * CIN + c) * NTAP + n]);
}

// x transpose: xT[pos][c] bf16 (coalesced read via LDS, 16B stores)
__global__ __launch_bounds__(256) void xtrans_kernel(
        const float* __restrict__ x, unsigned short* __restrict__ xT)
{
    __shared__ float t[CIN][65];
    const int p0 = blockIdx.x * 64;
    const int tid = threadIdx.x;
    const int tx = tid & 63, ty = tid >> 6;
    #pragma unroll
    for (int k = 0; k < 8; ++k) {
        int c = ty + k * 4;
        t[c][tx] = x[(size_t)c * SPATIAL + p0 + tx];
    }
    __syncthreads();
    const int pl = tid >> 2, cg = (tid & 3) * 8;
    short8 v;
    #pragma unroll
    for (int i = 0; i < 8; ++i) v[i] = (short)f2bf(t[cg + i][pl]);
    *(short8*)&xT[((size_t)(p0 + pl)) * 32 + cg] = v;
}

// ---------------- Fused kernel, tap-split wave pairs ----------------
// Block = 4 waves over 32 positions: wv = pg + 2*ts.
//   pg (0/1): position group of 16;  ts (0/1): deform taps 0..13 / 14..26.
// Phase 1: conv, each wave computes its own 3 j-blocks (oc' tap-major).
// Phase 2: D-frags -> wave-local LDS offl[wv][16][50].
// Phase 3: trilinear gather + bf16 MFMA einsum over the wave's taps.
// Phase 4: ts=1 writes partial accs to LDS; ts=0 adds and stores.
__global__ __launch_bounds__(256, 8) void fused_deform2(
        const unsigned short* __restrict__ xT,    // [SPATIAL][32] bf16
        const unsigned short* __restrict__ Bp2,
        const unsigned short* __restrict__ wpk,
        float* __restrict__ out)                  // [32][SPATIAL] f32
{
    __shared__ float offl[4][16][50];             // 12.8 KB
    __shared__ f32x4 redv[2][64][2];              // 4 KB

    const int tid  = threadIdx.x;
    const int lane = tid & 63, wv = tid >> 6;
    const int pg   = wv & 1, ts = wv >> 1;
    const int p0   = blockIdx.x * 32 + pg * 16;
    const int kg   = lane >> 4;
    const int row  = lane & 15;
    const int pos  = p0 + row;
    const int w = pos % WW, h = (pos / WW) % HH, d = pos / (WW * HH);

    const short8* Xv  = (const short8*)xT;
    const short8* Bv  = (const short8*)Bp2;
    const short8* wv8 = (const short8*)wpk;

    // ---------------- phase 1: offset conv (3 j-blocks per wave) ----------------
    f32x4 cacc[3];
    #pragma unroll
    for (int j = 0; j < 3; ++j) cacc[j] = (f32x4){0.f, 0.f, 0.f, 0.f};

    {
        int n = 0;
        #pragma unroll 1
        for (int td = -1; td <= 1; ++td) {
            #pragma unroll 1
            for (int th = -1; th <= 1; ++th) {
                #pragma unroll
                for (int tw = -1; tw <= 1; ++tw, ++n) {
                    bool valid = ((unsigned)(d + td) < DD)
                               & ((unsigned)(h + th) < HH)
                               & ((unsigned)(w + tw) < WW);
                    int dpos = pos + td * 2304 + th * 48 + tw;
                    short8 af = {0, 0, 0, 0, 0, 0, 0, 0};
                    if (valid) af = Xv[dpos * 4 + kg];
                    #pragma unroll
                    for (int jl = 0; jl < 3; ++jl)
                        cacc[jl] = __builtin_amdgcn_mfma_f32_16x16x32_bf16(
                            af, Bv[(n * 6 + ts * 3 + jl) * 64 + lane], cacc[jl], 0, 0, 0);
                }
            }
        }
    }

    // ---------------- phase 2: D-frags -> wave-local LDS ----------------
    // D: row(pos_local) = kg*4+r, col(oc'_local) = jl*16+row
    #pragma unroll
    for (int jl = 0; jl < 3; ++jl) {
        #pragma unroll
        for (int r = 0; r < 4; ++r)
            offl[wv][kg * 4 + r][jl * 16 + row] = cacc[jl][r];
    }
    __syncthreads();

    // ---------------- phase 3: deform gather + einsum ----------------
    const float* ol = &offl[wv][row][0];
    const int NT    = ts ? 13 : 14;
    const int nbase = ts * 14;

    f32x4 acc0 = {0.f, 0.f, 0.f, 0.f};
    f32x4 acc1 = {0.f, 0.f, 0.f, 0.f};

    #pragma unroll 1
    for (int nl = 0; nl < NT; ++nl) {
        const int nn = nbase + nl;
        float od = ol[nl * 3 + 0];
        float oh = ol[nl * 3 + 1];
        float ow = ol[nl * 3 + 2];
        float rd = (float)(nn / 9) - 1.f;
        float rh = (float)((nn / 3) % 3) - 1.f;
        float rw = (float)(nn % 3) - 1.f;

        float pdp = (float)(d + 1) + rd + od;
        float php = (float)(h + 1) + rh + oh;
        float pwp = (float)(w + 1) + rw + ow;

        float fd = floorf(pdp), fh = floorf(php), fw = floorf(pwp);
        float qd0 = fminf(fmaxf(fd,       0.f), 33.f);
        float qd1 = fminf(fmaxf(fd + 1.f, 0.f), 33.f);
        float qh0 = fminf(fmaxf(fh,       0.f), 49.f);
        float qh1 = fminf(fmaxf(fh + 1.f, 0.f), 49.f);
        float qw0 = fminf(fmaxf(fw,       0.f), 49.f);
        float qw1 = fminf(fmaxf(fw + 1.f, 0.f), 49.f);
        float pcd = fminf(fmaxf(pdp, 0.f), 33.f);
        float pch = fminf(fmaxf(php, 0.f), 49.f);
        float pcw = fminf(fmaxf(pwp, 0.f), 49.f);

        float gd0 = 1.f + (qd0 - pcd), gd1 = 1.f - (qd1 - pcd);
        float gh0 = 1.f + (qh0 - pch), gh1 = 1.f - (qh1 - pch);
        float gw0 = 1.f + (qw0 - pcw), gw1 = 1.f - (qw1 - pcw);
        // pad-corner semantics: zero the per-axis gain, clamp index to real range
        gd0 = (qd0 >= 1.f && qd0 <= 32.f) ? gd0 : 0.f;
        gd1 = (qd1 >= 1.f && qd1 <= 32.f) ? gd1 : 0.f;
        gh0 = (qh0 >= 1.f && qh0 <= 48.f) ? gh0 : 0.f;
        gh1 = (qh1 >= 1.f && qh1 <= 48.f) ? gh1 : 0.f;
        gw0 = (qw0 >= 1.f && qw0 <= 48.f) ? gw0 : 0.f;
        gw1 = (qw1 >= 1.f && qw1 <= 48.f) ? gw1 : 0.f;
        int zd0 = (int)fminf(fmaxf(qd0, 1.f), 32.f) - 1;
        int zd1 = (int)fminf(fmaxf(qd1, 1.f), 32.f) - 1;
        int zh0 = (int)fminf(fmaxf(qh0, 1.f), 48.f) - 1;
        int zh1 = (int)fminf(fmaxf(qh1, 1.f), 48.f) - 1;
        int zw0 = (int)fminf(fmaxf(qw0, 1.f), 48.f) - 1;
        int zw1 = (int)fminf(fmaxf(qw1, 1.f), 48.f) - 1;

        int bd0 = zd0 * 2304, bd1 = zd1 * 2304;
        int bh0 = zh0 * 48,   bh1 = zh1 * 48;
        float gdh00 = gd0 * gh0, gdh01 = gd0 * gh1;
        float gdh10 = gd1 * gh0, gdh11 = gd1 * gh1;

        int   bb[8]; float gg[8];
        bb[0] = bd0 + bh0 + zw0;  gg[0] = gdh00 * gw0;
        bb[1] = bd0 + bh0 + zw1;  gg[1] = gdh00 * gw1;
        bb[2] = bd0 + bh1 + zw0;  gg[2] = gdh01 * gw0;
        bb[3] = bd0 + bh1 + zw1;  gg[3] = gdh01 * gw1;
        bb[4] = bd1 + bh0 + zw0;  gg[4] = gdh10 * gw0;
        bb[5] = bd1 + bh0 + zw1;  gg[5] = gdh10 * gw1;
        bb[6] = bd1 + bh1 + zw0;  gg[6] = gdh11 * gw0;
        bb[7] = bd1 + bh1 + zw1;  gg[7] = gdh11 * gw1;

        float xo[8];
        #pragma unroll
        for (int i = 0; i < 8; ++i) xo[i] = 0.f;

        #pragma unroll
        for (int e = 0; e < 8; ++e) {
            short8 v8 = Xv[bb[e] * 4 + kg];
            float g = gg[e];
            #pragma unroll
            for (int i = 0; i < 8; ++i)
                xo[i] = fmaf(g, bf2f((unsigned short)v8[i]), xo[i]);
        }

        // pack A-fragment: v_cvt_pk_bf16_f32 (D.lo = bf16(S0), D.hi = bf16(S1))
        union { unsigned u[4]; short8 s; } av;
        #pragma unroll
        for (int i = 0; i < 4; ++i) {
            unsigned r;
            asm("v_cvt_pk_bf16_f32 %0, %1, %2"
                : "=v"(r) : "v"(xo[2 * i]), "v"(xo[2 * i + 1]));
            av.u[i] = r;
        }

        short8 b0 = wv8[(nn * 2 + 0) * 64 + lane];
        short8 b1 = wv8[(nn * 2 + 1) * 64 + lane];
        acc0 = __builtin_amdgcn_mfma_f32_16x16x32_bf16(av.s, b0, acc0, 0, 0, 0);
        acc1 = __builtin_amdgcn_mfma_f32_16x16x32_bf16(av.s, b1, acc1, 0, 0, 0);
    }

    // ---------------- phase 4: pair reduce + store ----------------
    if (ts) {
        redv[pg][lane][0] = acc0;
        redv[pg][lane][1] = acc1;
    }
    __syncthreads();
    if (!ts) {
        acc0 += redv[pg][lane][0];
        acc1 += redv[pg][lane][1];
        // D layout: col = lane&15 -> oc, row = kg*4+reg -> pos
        const int pb = p0 + kg * 4;
        *(f32x4*)&out[(size_t)row        * SPATIAL + pb] = acc0;
        *(f32x4*)&out[(size_t)(16 + row) * SPATIAL + pb] = acc1;
    }
}

// ----------------------------------------------------------------------------
extern "C" void kernel_launch(void* const* d_in, const int* in_sizes, int n_in,
                              void* d_out, int out_size, void* d_ws, size_t ws_size,
                              hipStream_t stream)
{
    const float* x     = (const float*)d_in[0];
    const float* w_off = (const float*)d_in[1];
    const float* w_def = (const float*)d_in[2];
    float* out = (float*)d_out;

    unsigned short* Bp2 = (unsigned short*)((char*)d_ws);
    unsigned short* wpk = (unsigned short*)((char*)d_ws + OFF_WPK);
    unsigned short* xT  = (unsigned short*)((char*)d_ws + OFF_XT);

    wprep2_kernel<<<(BP2_ELEMS + 255) / 256, 256, 0, stream>>>(w_off, Bp2);
    wdefprep_kernel<<<(WPK_ELEMS + 255) / 256, 256, 0, stream>>>(w_def, wpk);
    xtrans_kernel<<<SPATIAL / 64, 256, 0, stream>>>(x, xT);
    fused_deform2<<<SPATIAL / 32, 256, 0, stream>>>(xT, Bp2, wpk, out);
}

// Round 7
// 144.785 us; speedup vs baseline: 1.1518x; 1.1518x over previous
//
#include <hip/hip_runtime.h>

typedef __attribute__((ext_vector_type(8))) short  short8;
typedef __attribute__((ext_vector_type(4))) float  f32x4;
typedef __attribute__((ext_vector_type(2))) float  f32x2;

#define CIN 32
#define COUT 32
#define DD 32
#define HH 48
#define WW 48
#define NTAP 27
#define SPATIAL (DD*HH*WW)          // 73728

// ---- ws layout (bytes) ----
#define BP2_ELEMS (27*6*64*8)                       // conv B-pack: 82944
#define OFF_WPK   ((size_t)BP2_ELEMS*2)             // 165888
#define WPK_ELEMS (27*2*64*8)                       // einsum B-pack: 27648
#define OFF_XT    (OFF_WPK + (size_t)WPK_ELEMS*2)   // 221184 (16B aligned)
// xT bf16: 4,718,592 B -> total ~4.94 MB

__device__ __forceinline__ unsigned short f2bf(float f) {
    union { float f; unsigned u; } v; v.f = f;
    unsigned r = v.u + 0x7FFFu + ((v.u >> 16) & 1u);   // RNE
    return (unsigned short)(r >> 16);
}
__device__ __forceinline__ float bitsf(unsigned u) {
    union { unsigned u; float f; } v; v.u = u; return v.f;
}

// ---------------------------------------------------------------- prep kernels
// conv B-pack: Bp2[((n*6+j)*64+lane)*8+e] = bf16(w_off[j*16+col][kg*8+e][n])
__global__ __launch_bounds__(256) void wprep2_kernel(
        const float* __restrict__ w_off, unsigned short* __restrict__ Bp2)
{
    int i = blockIdx.x * 256 + threadIdx.x;
    if (i >= BP2_ELEMS) return;
    int e    = i & 7;
    int lane = (i >> 3) & 63;
    int j    = (i >> 9) % 6;
    int n    = i / (512 * 6);
    int col = lane & 15, kg = lane >> 4;
    int oc = j * 16 + col, c = kg * 8 + e;
    float v = (oc < 81) ? w_off[((size_t)oc * CIN + c) * NTAP + n] : 0.f;
    Bp2[i] = f2bf(v);
}

// einsum B-pack: wpk[((n*2+half)*64+lane)*8+e] = bf16(w_def[half*16+col][kg*8+e][n])
__global__ __launch_bounds__(256) void wdefprep_kernel(
        const float* __restrict__ w_def, unsigned short* __restrict__ wpk)
{
    int i = blockIdx.x * 256 + threadIdx.x;
    if (i >= WPK_ELEMS) return;
    int e    = i & 7;
    int lane = (i >> 3) & 63;
    int half = (i >> 9) & 1;
    int n    = i >> 10;
    int kg = lane >> 4, col = lane & 15;
    int c  = kg * 8 + e, oc = half * 16 + col;
    wpk[i] = f2bf(w_def[((size_t)oc * CIN + c) * NTAP + n]);
}

// x transpose: xT[pos][c] bf16 (coalesced read via LDS, 16B stores)
__global__ __launch_bounds__(256) void xtrans_kernel(
        const float* __restrict__ x, unsigned short* __restrict__ xT)
{
    __shared__ float t[CIN][65];
    const int p0 = blockIdx.x * 64;
    const int tid = threadIdx.x;
    const int tx = tid & 63, ty = tid >> 6;
    #pragma unroll
    for (int k = 0; k < 8; ++k) {
        int c = ty + k * 4;
        t[c][tx] = x[(size_t)c * SPATIAL + p0 + tx];
    }
    __syncthreads();
    const int pl = tid >> 2, cg = (tid & 3) * 8;
    short8 v;
    #pragma unroll
    for (int i = 0; i < 8; ++i) v[i] = (short)f2bf(t[cg + i][pl]);
    *(short8*)&xT[((size_t)(p0 + pl)) * 32 + cg] = v;
}

// ---------------- Fused kernel: offset conv (MFMA) -> LDS -> deform (MFMA)
// Wave owns 16 consecutive positions; 4 waves = 64 pos/block; 1152 blocks.
__global__ __launch_bounds__(256, 4) void fused_deform3(
        const unsigned short* __restrict__ xT,    // [SPATIAL][32] bf16
        const unsigned short* __restrict__ Bp2,
        const unsigned short* __restrict__ wpk,
        float* __restrict__ out)                  // [32][SPATIAL] f32
{
    __shared__ float offl[4][16][97];             // 24.8 KB

    const int tid  = threadIdx.x;
    const int lane = tid & 63, wv = tid >> 6;
    const int p0   = blockIdx.x * 64 + wv * 16;
    const int kg   = lane >> 4;
    const int row  = lane & 15;
    const int pos  = p0 + row;
    const int w = pos % WW, h = (pos / WW) % HH, d = pos / (WW * HH);

    const short8* Xv  = (const short8*)xT;
    const uint4*  Xu  = (const uint4*)xT;
    const short8* Bv  = (const short8*)Bp2;
    const short8* wv8 = (const short8*)wpk;

    // ---------------- phase 1: offset conv ----------------
    f32x4 cacc[6];
    #pragma unroll
    for (int j = 0; j < 6; ++j) cacc[j] = (f32x4){0.f, 0.f, 0.f, 0.f};
    {
        int n = 0;
        #pragma unroll 1
        for (int td = -1; td <= 1; ++td) {
            #pragma unroll 1
            for (int th = -1; th <= 1; ++th) {
                #pragma unroll
                for (int tw = -1; tw <= 1; ++tw, ++n) {
                    bool valid = ((unsigned)(d + td) < DD)
                               & ((unsigned)(h + th) < HH)
                               & ((unsigned)(w + tw) < WW);
                    int dpos = pos + td * 2304 + th * 48 + tw;
                    short8 af = {0, 0, 0, 0, 0, 0, 0, 0};
                    if (valid) af = Xv[dpos * 4 + kg];
                    #pragma unroll
                    for (int j = 0; j < 6; ++j)
                        cacc[j] = __builtin_amdgcn_mfma_f32_16x16x32_bf16(
                                      af, Bv[(n * 6 + j) * 64 + lane], cacc[j], 0, 0, 0);
                }
            }
        }
    }

    // ---------------- phase 2: D-frags -> wave-local LDS ----------------
    #pragma unroll
    for (int j = 0; j < 6; ++j) {
        #pragma unroll
        for (int r = 0; r < 4; ++r)
            offl[wv][kg * 4 + r][j * 16 + row] = cacc[j][r];
    }
    __syncthreads();

    // ---------------- phase 3: deform gather + einsum ----------------
    const float* ol = &offl[wv][row][0];

    f32x4 acc0 = {0.f, 0.f, 0.f, 0.f};
    f32x4 acc1 = {0.f, 0.f, 0.f, 0.f};

    // software-pipelined offset reads
    float od = ol[0], oh = ol[27], ow = ol[54];

    #pragma unroll 1
    for (int n = 0; n < NTAP; ++n) {
        // prefetch next tap's offsets (LDS) + this tap's B-frags (global)
        int np = (n < 26) ? n + 1 : 26;
        float odn = ol[np], ohn = ol[27 + np], own = ol[54 + np];
        short8 b0 = wv8[(n * 2 + 0) * 64 + lane];
        short8 b1 = wv8[(n * 2 + 1) * 64 + lane];

        float rd = (float)(n / 9) - 1.f;
        float rh = (float)((n / 3) % 3) - 1.f;
        float rw = (float)(n % 3) - 1.f;

        float pdp = (float)(d + 1) + rd + od;
        float php = (float)(h + 1) + rh + oh;
        float pwp = (float)(w + 1) + rw + ow;

        float fd = floorf(pdp), fh = floorf(php), fw = floorf(pwp);
        float qd0 = fminf(fmaxf(fd,       0.f), 33.f);
        float qd1 = fminf(fmaxf(fd + 1.f, 0.f), 33.f);
        float qh0 = fminf(fmaxf(fh,       0.f), 49.f);
        float qh1 = fminf(fmaxf(fh + 1.f, 0.f), 49.f);
        float qw0 = fminf(fmaxf(fw,       0.f), 49.f);
        float qw1 = fminf(fmaxf(fw + 1.f, 0.f), 49.f);
        float pcd = fminf(fmaxf(pdp, 0.f), 33.f);
        float pch = fminf(fmaxf(php, 0.f), 49.f);
        float pcw = fminf(fmaxf(pwp, 0.f), 49.f);

        float gd0 = 1.f + (qd0 - pcd), gd1 = 1.f - (qd1 - pcd);
        float gh0 = 1.f + (qh0 - pch), gh1 = 1.f - (qh1 - pch);
        float gw0 = 1.f + (qw0 - pcw), gw1 = 1.f - (qw1 - pcw);
        // pad-corner semantics: zero per-axis gain, clamp index to real range
        gd0 = (qd0 >= 1.f && qd0 <= 32.f) ? gd0 : 0.f;
        gd1 = (qd1 >= 1.f && qd1 <= 32.f) ? gd1 : 0.f;
        gh0 = (qh0 >= 1.f && qh0 <= 48.f) ? gh0 : 0.f;
        gh1 = (qh1 >= 1.f && qh1 <= 48.f) ? gh1 : 0.f;
        gw0 = (qw0 >= 1.f && qw0 <= 48.f) ? gw0 : 0.f;
        gw1 = (qw1 >= 1.f && qw1 <= 48.f) ? gw1 : 0.f;
        int zd0 = (int)fminf(fmaxf(qd0, 1.f), 32.f) - 1;
        int zd1 = (int)fminf(fmaxf(qd1, 1.f), 32.f) - 1;
        int zh0 = (int)fminf(fmaxf(qh0, 1.f), 48.f) - 1;
        int zh1 = (int)fminf(fmaxf(qh1, 1.f), 48.f) - 1;
        int zw0 = (int)fminf(fmaxf(qw0, 1.f), 48.f) - 1;
        int zw1 = (int)fminf(fmaxf(qw1, 1.f), 48.f) - 1;

        int bd0 = zd0 * 2304, bd1 = zd1 * 2304;
        int bh0 = zh0 * 48,   bh1 = zh1 * 48;
        float gdh00 = gd0 * gh0, gdh01 = gd0 * gh1;
        float gdh10 = gd1 * gh0, gdh11 = gd1 * gh1;

        int   bb[8]; float gg[8];
        bb[0] = bd0 + bh0 + zw0;  gg[0] = gdh00 * gw0;
        bb[1] = bd0 + bh0 + zw1;  gg[1] = gdh00 * gw1;
        bb[2] = bd0 + bh1 + zw0;  gg[2] = gdh01 * gw0;
        bb[3] = bd0 + bh1 + zw1;  gg[3] = gdh01 * gw1;
        bb[4] = bd1 + bh0 + zw0;  gg[4] = gdh10 * gw0;
        bb[5] = bd1 + bh0 + zw1;  gg[5] = gdh10 * gw1;
        bb[6] = bd1 + bh1 + zw0;  gg[6] = gdh11 * gw0;
        bb[7] = bd1 + bh1 + zw1;  gg[7] = gdh11 * gw1;

        // batch all 8 corner loads into registers (force MLP)
        uint4 cw0 = Xu[bb[0] * 4 + kg];
        uint4 cw1 = Xu[bb[1] * 4 + kg];
        uint4 cw2 = Xu[bb[2] * 4 + kg];
        uint4 cw3 = Xu[bb[3] * 4 + kg];
        uint4 cw4 = Xu[bb[4] * 4 + kg];
        uint4 cw5 = Xu[bb[5] * 4 + kg];
        uint4 cw6 = Xu[bb[6] * 4 + kg];
        uint4 cw7 = Xu[bb[7] * 4 + kg];

        f32x2 xa0 = {0.f, 0.f}, xa1 = {0.f, 0.f};
        f32x2 xa2 = {0.f, 0.f}, xa3 = {0.f, 0.f};

        #define ACC_CORNER(CW, G)                                              \
        {                                                                      \
            f32x2 g2 = {(G), (G)};                                             \
            f32x2 v0 = {bitsf(CW.x << 16), bitsf(CW.x & 0xFFFF0000u)};         \
            f32x2 v1 = {bitsf(CW.y << 16), bitsf(CW.y & 0xFFFF0000u)};         \
            f32x2 v2 = {bitsf(CW.z << 16), bitsf(CW.z & 0xFFFF0000u)};         \
            f32x2 v3 = {bitsf(CW.w << 16), bitsf(CW.w & 0xFFFF0000u)};         \
            asm("v_pk_fma_f32 %0, %1, %2, %0" : "+v"(xa0) : "v"(v0), "v"(g2)); \
            asm("v_pk_fma_f32 %0, %1, %2, %0" : "+v"(xa1) : "v"(v1), "v"(g2)); \
            asm("v_pk_fma_f32 %0, %1, %2, %0" : "+v"(xa2) : "v"(v2), "v"(g2)); \
            asm("v_pk_fma_f32 %0, %1, %2, %0" : "+v"(xa3) : "v"(v3), "v"(g2)); \
        }
        ACC_CORNER(cw0, gg[0]); ACC_CORNER(cw1, gg[1]);
        ACC_CORNER(cw2, gg[2]); ACC_CORNER(cw3, gg[3]);
        ACC_CORNER(cw4, gg[4]); ACC_CORNER(cw5, gg[5]);
        ACC_CORNER(cw6, gg[6]); ACC_CORNER(cw7, gg[7]);
        #undef ACC_CORNER

        // pack A-fragment: v_cvt_pk_bf16_f32
        union { unsigned u[4]; short8 s; } av;
        asm("v_cvt_pk_bf16_f32 %0, %1, %2" : "=v"(av.u[0]) : "v"(xa0.x), "v"(xa0.y));
        asm("v_cvt_pk_bf16_f32 %0, %1, %2" : "=v"(av.u[1]) : "v"(xa1.x), "v"(xa1.y));
        asm("v_cvt_pk_bf16_f32 %0, %1, %2" : "=v"(av.u[2]) : "v"(xa2.x), "v"(xa2.y));
        asm("v_cvt_pk_bf16_f32 %0, %1, %2" : "=v"(av.u[3]) : "v"(xa3.x), "v"(xa3.y));

        acc0 = __builtin_amdgcn_mfma_f32_16x16x32_bf16(av.s, b0, acc0, 0, 0, 0);
        acc1 = __builtin_amdgcn_mfma_f32_16x16x32_bf16(av.s, b1, acc1, 0, 0, 0);

        od = odn; oh = ohn; ow = own;
    }

    // D layout: col = lane&15 -> oc, row = kg*4+reg -> pos
    const int pb = p0 + kg * 4;
    *(f32x4*)&out[(size_t)row        * SPATIAL + pb] = acc0;
    *(f32x4*)&out[(size_t)(16 + row) * SPATIAL + pb] = acc1;
}

// ----------------------------------------------------------------------------
extern "C" void kernel_launch(void* const* d_in, const int* in_sizes, int n_in,
                              void* d_out, int out_size, void* d_ws, size_t ws_size,
                              hipStream_t stream)
{
    const float* x     = (const float*)d_in[0];
    const float* w_off = (const float*)d_in[1];
    const float* w_def = (const float*)d_in[2];
    float* out = (float*)d_out;

    unsigned short* Bp2 = (unsigned short*)((char*)d_ws);
    unsigned short* wpk = (unsigned short*)((char*)d_ws + OFF_WPK);
    unsigned short* xT  = (unsigned short*)((char*)d_ws + OFF_XT);

    wprep2_kernel<<<(BP2_ELEMS + 255) / 256, 256, 0, stream>>>(w_off, Bp2);
    wdefprep_kernel<<<(WPK_ELEMS + 255) / 256, 256, 0, stream>>>(w_def, wpk);
    xtrans_kernel<<<SPATIAL / 64, 256, 0, stream>>>(x, xT);
    fused_deform3<<<SPATIAL / 64, 256, 0, stream>>>(xT, Bp2, wpk, out);
}

// Round 8
// 141.155 us; speedup vs baseline: 1.1814x; 1.0257x over previous
//
#include <hip/hip_runtime.h>

typedef __attribute__((ext_vector_type(8))) short  short8;
typedef __attribute__((ext_vector_type(4))) float  f32x4;
typedef __attribute__((ext_vector_type(2))) float  f32x2;

#define CIN 32
#define COUT 32
#define DD 32
#define HH 48
#define WW 48
#define NTAP 27
#define SPATIAL (DD*HH*WW)          // 73728

// ---- ws layout (bytes) ----
#define BP2_ELEMS (27*6*64*8)                       // conv B-pack: 82944
#define OFF_WPK   ((size_t)BP2_ELEMS*2)             // 165888
#define WPK_ELEMS (27*2*64*8)                       // einsum B-pack: 27648
#define OFF_XT    (OFF_WPK + (size_t)WPK_ELEMS*2)   // 221184 (16B aligned)
// xT bf16: 4,718,592 B -> total ~4.94 MB

__device__ __forceinline__ unsigned short f2bf(float f) {
    union { float f; unsigned u; } v; v.f = f;
    unsigned r = v.u + 0x7FFFu + ((v.u >> 16) & 1u);   // RNE
    return (unsigned short)(r >> 16);
}
__device__ __forceinline__ float bitsf(unsigned u) {
    union { unsigned u; float f; } v; v.u = u; return v.f;
}

// ---------------------------------------------------------------- prep kernels
// conv B-pack: Bp2[((n*6+j)*64+lane)*8+e] = bf16(w_off[j*16+col][kg*8+e][n])
__global__ __launch_bounds__(256) void wprep2_kernel(
        const float* __restrict__ w_off, unsigned short* __restrict__ Bp2)
{
    int i = blockIdx.x * 256 + threadIdx.x;
    if (i >= BP2_ELEMS) return;
    int e    = i & 7;
    int lane = (i >> 3) & 63;
    int j    = (i >> 9) % 6;
    int n    = i / (512 * 6);
    int col = lane & 15, kg = lane >> 4;
    int oc = j * 16 + col, c = kg * 8 + e;
    float v = (oc < 81) ? w_off[((size_t)oc * CIN + c) * NTAP + n] : 0.f;
    Bp2[i] = f2bf(v);
}

// einsum B-pack: wpk[((n*2+half)*64+lane)*8+e] = bf16(w_def[half*16+col][kg*8+e][n])
__global__ __launch_bounds__(256) void wdefprep_kernel(
        const float* __restrict__ w_def, unsigned short* __restrict__ wpk)
{
    int i = blockIdx.x * 256 + threadIdx.x;
    if (i >= WPK_ELEMS) return;
    int e    = i & 7;
    int lane = (i >> 3) & 63;
    int half = (i >> 9) & 1;
    int n    = i >> 10;
    int kg = lane >> 4, col = lane & 15;
    int c  = kg * 8 + e, oc = half * 16 + col;
    wpk[i] = f2bf(w_def[((size_t)oc * CIN + c) * NTAP + n]);
}

// x transpose: xT[pos][c] bf16 (coalesced read via LDS, 16B stores)
__global__ __launch_bounds__(256) void xtrans_kernel(
        const float* __restrict__ x, unsigned short* __restrict__ xT)
{
    __shared__ float t[CIN][65];
    const int p0 = blockIdx.x * 64;
    const int tid = threadIdx.x;
    const int tx = tid & 63, ty = tid >> 6;
    #pragma unroll
    for (int k = 0; k < 8; ++k) {
        int c = ty + k * 4;
        t[c][tx] = x[(size_t)c * SPATIAL + p0 + tx];
    }
    __syncthreads();
    const int pl = tid >> 2, cg = (tid & 3) * 8;
    short8 v;
    #pragma unroll
    for (int i = 0; i < 8; ++i) v[i] = (short)f2bf(t[cg + i][pl]);
    *(short8*)&xT[((size_t)(p0 + pl)) * 32 + cg] = v;
}

// ---------------------------------------------------------------- tap pipeline
struct TapBuf {
    uint4 cw[8];    // 8 corner loads in flight
    float gg[8];    // corner gains
};

__device__ __forceinline__ void tap_issue(
        TapBuf& tb, const uint4* __restrict__ Xu, const float* __restrict__ ol,
        int n, int d, int h, int w, int kg)
{
    float od = ol[n], oh = ol[27 + n], ow = ol[54 + n];
    float rd = (float)(n / 9) - 1.f;
    float rh = (float)((n / 3) % 3) - 1.f;
    float rw = (float)(n % 3) - 1.f;

    float pdp = (float)(d + 1) + rd + od;
    float php = (float)(h + 1) + rh + oh;
    float pwp = (float)(w + 1) + rw + ow;

    float fd = floorf(pdp), fh = floorf(php), fw = floorf(pwp);
    float qd0 = fminf(fmaxf(fd,       0.f), 33.f);
    float qd1 = fminf(fmaxf(fd + 1.f, 0.f), 33.f);
    float qh0 = fminf(fmaxf(fh,       0.f), 49.f);
    float qh1 = fminf(fmaxf(fh + 1.f, 0.f), 49.f);
    float qw0 = fminf(fmaxf(fw,       0.f), 49.f);
    float qw1 = fminf(fmaxf(fw + 1.f, 0.f), 49.f);
    float pcd = fminf(fmaxf(pdp, 0.f), 33.f);
    float pch = fminf(fmaxf(php, 0.f), 49.f);
    float pcw = fminf(fmaxf(pwp, 0.f), 49.f);

    float gd0 = 1.f + (qd0 - pcd), gd1 = 1.f - (qd1 - pcd);
    float gh0 = 1.f + (qh0 - pch), gh1 = 1.f - (qh1 - pch);
    float gw0 = 1.f + (qw0 - pcw), gw1 = 1.f - (qw1 - pcw);
    // pad-corner semantics: zero per-axis gain, clamp index to real range
    gd0 = (qd0 >= 1.f && qd0 <= 32.f) ? gd0 : 0.f;
    gd1 = (qd1 >= 1.f && qd1 <= 32.f) ? gd1 : 0.f;
    gh0 = (qh0 >= 1.f && qh0 <= 48.f) ? gh0 : 0.f;
    gh1 = (qh1 >= 1.f && qh1 <= 48.f) ? gh1 : 0.f;
    gw0 = (qw0 >= 1.f && qw0 <= 48.f) ? gw0 : 0.f;
    gw1 = (qw1 >= 1.f && qw1 <= 48.f) ? gw1 : 0.f;
    int zd0 = (int)fminf(fmaxf(qd0, 1.f), 32.f) - 1;
    int zd1 = (int)fminf(fmaxf(qd1, 1.f), 32.f) - 1;
    int zh0 = (int)fminf(fmaxf(qh0, 1.f), 48.f) - 1;
    int zh1 = (int)fminf(fmaxf(qh1, 1.f), 48.f) - 1;
    int zw0 = (int)fminf(fmaxf(qw0, 1.f), 48.f) - 1;
    int zw1 = (int)fminf(fmaxf(qw1, 1.f), 48.f) - 1;

    int bd0 = zd0 * 2304, bd1 = zd1 * 2304;
    int bh0 = zh0 * 48,   bh1 = zh1 * 48;
    float gdh00 = gd0 * gh0, gdh01 = gd0 * gh1;
    float gdh10 = gd1 * gh0, gdh11 = gd1 * gh1;

    int bb[8];
    bb[0] = bd0 + bh0 + zw0;  tb.gg[0] = gdh00 * gw0;
    bb[1] = bd0 + bh0 + zw1;  tb.gg[1] = gdh00 * gw1;
    bb[2] = bd0 + bh1 + zw0;  tb.gg[2] = gdh01 * gw0;
    bb[3] = bd0 + bh1 + zw1;  tb.gg[3] = gdh01 * gw1;
    bb[4] = bd1 + bh0 + zw0;  tb.gg[4] = gdh10 * gw0;
    bb[5] = bd1 + bh0 + zw1;  tb.gg[5] = gdh10 * gw1;
    bb[6] = bd1 + bh1 + zw0;  tb.gg[6] = gdh11 * gw0;
    bb[7] = bd1 + bh1 + zw1;  tb.gg[7] = gdh11 * gw1;

    #pragma unroll
    for (int e = 0; e < 8; ++e)
        tb.cw[e] = Xu[bb[e] * 4 + kg];
}

__device__ __forceinline__ void tap_consume(
        const TapBuf& tb, const short8* __restrict__ wv8,
        int n, int lane, f32x4& acc0, f32x4& acc1)
{
    short8 b0 = wv8[(n * 2 + 0) * 64 + lane];
    short8 b1 = wv8[(n * 2 + 1) * 64 + lane];

    f32x2 xa0 = {0.f, 0.f}, xa1 = {0.f, 0.f};
    f32x2 xa2 = {0.f, 0.f}, xa3 = {0.f, 0.f};

    #pragma unroll
    for (int e = 0; e < 8; ++e) {
        uint4 cw = tb.cw[e];
        f32x2 g2 = {tb.gg[e], tb.gg[e]};
        f32x2 v0 = {bitsf(cw.x << 16), bitsf(cw.x & 0xFFFF0000u)};
        f32x2 v1 = {bitsf(cw.y << 16), bitsf(cw.y & 0xFFFF0000u)};
        f32x2 v2 = {bitsf(cw.z << 16), bitsf(cw.z & 0xFFFF0000u)};
        f32x2 v3 = {bitsf(cw.w << 16), bitsf(cw.w & 0xFFFF0000u)};
        asm("v_pk_fma_f32 %0, %1, %2, %0" : "+v"(xa0) : "v"(v0), "v"(g2));
        asm("v_pk_fma_f32 %0, %1, %2, %0" : "+v"(xa1) : "v"(v1), "v"(g2));
        asm("v_pk_fma_f32 %0, %1, %2, %0" : "+v"(xa2) : "v"(v2), "v"(g2));
        asm("v_pk_fma_f32 %0, %1, %2, %0" : "+v"(xa3) : "v"(v3), "v"(g2));
    }

    union { unsigned u[4]; short8 s; } av;
    asm("v_cvt_pk_bf16_f32 %0, %1, %2" : "=v"(av.u[0]) : "v"(xa0.x), "v"(xa0.y));
    asm("v_cvt_pk_bf16_f32 %0, %1, %2" : "=v"(av.u[1]) : "v"(xa1.x), "v"(xa1.y));
    asm("v_cvt_pk_bf16_f32 %0, %1, %2" : "=v"(av.u[2]) : "v"(xa2.x), "v"(xa2.y));
    asm("v_cvt_pk_bf16_f32 %0, %1, %2" : "=v"(av.u[3]) : "v"(xa3.x), "v"(xa3.y));

    acc0 = __builtin_amdgcn_mfma_f32_16x16x32_bf16(av.s, b0, acc0, 0, 0, 0);
    acc1 = __builtin_amdgcn_mfma_f32_16x16x32_bf16(av.s, b1, acc1, 0, 0, 0);
}

// ---------------- Fused kernel: offset conv (MFMA) -> LDS -> deform (MFMA)
// 2-wave blocks (32 pos); per-wave 16 pos; 2-deep pipelined taps.
__global__ __launch_bounds__(128, 4) void fused_deform4(
        const unsigned short* __restrict__ xT,    // [SPATIAL][32] bf16
        const unsigned short* __restrict__ Bp2,
        const unsigned short* __restrict__ wpk,
        float* __restrict__ out)                  // [32][SPATIAL] f32
{
    __shared__ float offl[2][16][97];             // 12.4 KB

    const int tid  = threadIdx.x;
    const int lane = tid & 63, wv = tid >> 6;
    const int p0   = blockIdx.x * 32 + wv * 16;
    const int kg   = lane >> 4;
    const int row  = lane & 15;
    const int pos  = p0 + row;
    const int w = pos % WW, h = (pos / WW) % HH, d = pos / (WW * HH);

    const short8* Xv  = (const short8*)xT;
    const uint4*  Xu  = (const uint4*)xT;
    const short8* Bv  = (const short8*)Bp2;
    const short8* wv8 = (const short8*)wpk;

    // ---------------- phase 1: offset conv (2-deep A pipeline) ----------------
    f32x4 cacc[6];
    #pragma unroll
    for (int j = 0; j < 6; ++j) cacc[j] = (f32x4){0.f, 0.f, 0.f, 0.f};

    auto conv_load = [&](int n) -> short8 {
        int td = n / 9, th = (n / 3) % 3, tw = n % 3;
        bool valid = ((unsigned)(d + td - 1) < DD)
                   & ((unsigned)(h + th - 1) < HH)
                   & ((unsigned)(w + tw - 1) < WW);
        int dpos = pos + (td - 1) * 2304 + (th - 1) * 48 + (tw - 1);
        short8 af = {0, 0, 0, 0, 0, 0, 0, 0};
        if (valid) af = Xv[dpos * 4 + kg];
        return af;
    };

    {
        short8 afA = conv_load(0);
        #pragma unroll 1
        for (int n = 0; n < 26; n += 2) {
            short8 afB = conv_load(n + 1);
            #pragma unroll
            for (int j = 0; j < 6; ++j)
                cacc[j] = __builtin_amdgcn_mfma_f32_16x16x32_bf16(
                              afA, Bv[(n * 6 + j) * 64 + lane], cacc[j], 0, 0, 0);
            afA = conv_load(n + 2);
            #pragma unroll
            for (int j = 0; j < 6; ++j)
                cacc[j] = __builtin_amdgcn_mfma_f32_16x16x32_bf16(
                              afB, Bv[((n + 1) * 6 + j) * 64 + lane], cacc[j], 0, 0, 0);
        }
        #pragma unroll
        for (int j = 0; j < 6; ++j)
            cacc[j] = __builtin_amdgcn_mfma_f32_16x16x32_bf16(
                          afA, Bv[(26 * 6 + j) * 64 + lane], cacc[j], 0, 0, 0);
    }

    // ---------------- phase 2: D-frags -> wave-local LDS ----------------
    #pragma unroll
    for (int j = 0; j < 6; ++j) {
        #pragma unroll
        for (int r = 0; r < 4; ++r)
            offl[wv][kg * 4 + r][j * 16 + row] = cacc[j][r];
    }
    __syncthreads();

    // ---------------- phase 3: pipelined deform gather + einsum ----------------
    const float* ol = &offl[wv][row][0];

    f32x4 acc0 = {0.f, 0.f, 0.f, 0.f};
    f32x4 acc1 = {0.f, 0.f, 0.f, 0.f};

    TapBuf bufA, bufB;
    tap_issue(bufA, Xu, ol, 0, d, h, w, kg);
    #pragma unroll 1
    for (int n = 0; n < 26; n += 2) {
        tap_issue(bufB, Xu, ol, n + 1, d, h, w, kg);
        tap_consume(bufA, wv8, n, lane, acc0, acc1);
        tap_issue(bufA, Xu, ol, n + 2, d, h, w, kg);
        tap_consume(bufB, wv8, n + 1, lane, acc0, acc1);
    }
    tap_consume(bufA, wv8, 26, lane, acc0, acc1);

    // D layout: col = lane&15 -> oc, row = kg*4+reg -> pos
    const int pb = p0 + kg * 4;
    *(f32x4*)&out[(size_t)row        * SPATIAL + pb] = acc0;
    *(f32x4*)&out[(size_t)(16 + row) * SPATIAL + pb] = acc1;
}

// ----------------------------------------------------------------------------
extern "C" void kernel_launch(void* const* d_in, const int* in_sizes, int n_in,
                              void* d_out, int out_size, void* d_ws, size_t ws_size,
                              hipStream_t stream)
{
    const float* x     = (const float*)d_in[0];
    const float* w_off = (const float*)d_in[1];
    const float* w_def = (const float*)d_in[2];
    float* out = (float*)d_out;

    unsigned short* Bp2 = (unsigned short*)((char*)d_ws);
    unsigned short* wpk = (unsigned short*)((char*)d_ws + OFF_WPK);
    unsigned short* xT  = (unsigned short*)((char*)d_ws + OFF_XT);

    wprep2_kernel<<<(BP2_ELEMS + 255) / 256, 256, 0, stream>>>(w_off, Bp2);
    wdefprep_kernel<<<(WPK_ELEMS + 255) / 256, 256, 0, stream>>>(w_def, wpk);
    xtrans_kernel<<<SPATIAL / 64, 256, 0, stream>>>(x, xT);
    fused_deform4<<<SPATIAL / 32, 128, 0, stream>>>(xT, Bp2, wpk, out);
}

// Round 10
// 135.012 us; speedup vs baseline: 1.2352x; 1.0455x over previous
//
#include <hip/hip_runtime.h>

typedef __attribute__((ext_vector_type(8))) short  short8;
typedef __attribute__((ext_vector_type(4))) float  f32x4;
typedef __attribute__((ext_vector_type(2))) float  f32x2;

#define CIN 32
#define COUT 32
#define DD 32
#define HH 48
#define WW 48
#define NTAP 27
#define SPATIAL (DD*HH*WW)          // 73728

// ---- ws layout (bytes) ----
#define BP2_ELEMS (27*6*64*8)                       // conv B-pack: 82944
#define OFF_WPK   ((size_t)BP2_ELEMS*2)             // 165888
#define WPK_ELEMS (27*2*64*8)                       // einsum B-pack: 27648
#define OFF_XT    (OFF_WPK + (size_t)WPK_ELEMS*2)   // 221184 (16B aligned)
// xT bf16: 4,718,592 B -> total ~4.94 MB

#define SB0() __builtin_amdgcn_sched_barrier(0)

__device__ __forceinline__ unsigned short f2bf(float f) {
    union { float f; unsigned u; } v; v.f = f;
    unsigned r = v.u + 0x7FFFu + ((v.u >> 16) & 1u);   // RNE
    return (unsigned short)(r >> 16);
}
__device__ __forceinline__ float bitsf(unsigned u) {
    union { unsigned u; float f; } v; v.u = u; return v.f;
}

// ---------------------------------------------------------------- prep kernels
// conv B-pack: Bp2[((n*6+j)*64+lane)*8+e] = bf16(w_off[j*16+col][kg*8+e][n])
__global__ __launch_bounds__(256) void wprep2_kernel(
        const float* __restrict__ w_off, unsigned short* __restrict__ Bp2)
{
    int i = blockIdx.x * 256 + threadIdx.x;
    if (i >= BP2_ELEMS) return;
    int e    = i & 7;
    int lane = (i >> 3) & 63;
    int j    = (i >> 9) % 6;
    int n    = i / (512 * 6);
    int col = lane & 15, kg = lane >> 4;
    int oc = j * 16 + col, c = kg * 8 + e;
    float v = (oc < 81) ? w_off[((size_t)oc * CIN + c) * NTAP + n] : 0.f;
    Bp2[i] = f2bf(v);
}

// einsum B-pack: wpk[((n*2+half)*64+lane)*8+e] = bf16(w_def[half*16+col][kg*8+e][n])
__global__ __launch_bounds__(256) void wdefprep_kernel(
        const float* __restrict__ w_def, unsigned short* __restrict__ wpk)
{
    int i = blockIdx.x * 256 + threadIdx.x;
    if (i >= WPK_ELEMS) return;
    int e    = i & 7;
    int lane = (i >> 3) & 63;
    int half = (i >> 9) & 1;
    int n    = i >> 10;
    int kg = lane >> 4, col = lane & 15;
    int c  = kg * 8 + e, oc = half * 16 + col;
    wpk[i] = f2bf(w_def[((size_t)oc * CIN + c) * NTAP + n]);
}

// x transpose: xT[pos][c] bf16 (coalesced read via LDS, 16B stores)
__global__ __launch_bounds__(256) void xtrans_kernel(
        const float* __restrict__ x, unsigned short* __restrict__ xT)
{
    __shared__ float t[CIN][65];
    const int p0 = blockIdx.x * 64;
    const int tid = threadIdx.x;
    const int tx = tid & 63, ty = tid >> 6;
    #pragma unroll
    for (int k = 0; k < 8; ++k) {
        int c = ty + k * 4;
        t[c][tx] = x[(size_t)c * SPATIAL + p0 + tx];
    }
    __syncthreads();
    const int pl = tid >> 2, cg = (tid & 3) * 8;
    short8 v;
    #pragma unroll
    for (int i = 0; i < 8; ++i) v[i] = (short)f2bf(t[cg + i][pl]);
    *(short8*)&xT[((size_t)(p0 + pl)) * 32 + cg] = v;
}

// ---------------------------------------------------------------- in-flight bufs
struct ConvT {
    uint4 a;
    uint4 wt[6];
    int   valid;
};

struct Gath {
    uint4 cw[8];
    uint4 wb0, wb1;
    float gg[8];
};

__device__ __forceinline__ void conv_issue(
        ConvT& ct, const uint4* __restrict__ Xu, const uint4* __restrict__ Bu,
        int n, int pos, int d, int h, int w, int kg, int lane)
{
    int td = n / 9, th = (n / 3) % 3, tw = n % 3;
    int valid = ((unsigned)(d + td - 1) < DD)
              & ((unsigned)(h + th - 1) < HH)
              & ((unsigned)(w + tw - 1) < WW);
    int dpos = pos + (td - 1) * 2304 + (th - 1) * 48 + (tw - 1);
    int safe = valid ? dpos : pos;                 // always in-bounds
    ct.a = Xu[(size_t)safe * 4 + kg];
    #pragma unroll
    for (int j = 0; j < 6; ++j)
        ct.wt[j] = Bu[(size_t)(n * 6 + j) * 64 + lane];
    ct.valid = valid;
}

__device__ __forceinline__ void conv_consume(const ConvT& ct, f32x4* cacc)
{
    uint4 a = ct.a;
    if (!ct.valid) { a.x = 0; a.y = 0; a.z = 0; a.w = 0; }
    union { uint4 u; short8 s; } av; av.u = a;
    #pragma unroll
    for (int j = 0; j < 6; ++j) {
        union { uint4 u; short8 s; } b; b.u = ct.wt[j];
        cacc[j] = __builtin_amdgcn_mfma_f32_16x16x32_bf16(av.s, b.s, cacc[j], 0, 0, 0);
    }
}

__device__ __forceinline__ void tap_issue(
        Gath& tb, const uint4* __restrict__ Xu, const uint4* __restrict__ Wu,
        float od, float oh, float ow,
        int n, int d, int h, int w, int kg, int lane)
{
    float rd = (float)(n / 9) - 1.f;
    float rh = (float)((n / 3) % 3) - 1.f;
    float rw = (float)(n % 3) - 1.f;

    float pdp = (float)(d + 1) + rd + od;
    float php = (float)(h + 1) + rh + oh;
    float pwp = (float)(w + 1) + rw + ow;

    float fd = floorf(pdp), fh = floorf(php), fw = floorf(pwp);
    float qd0 = fminf(fmaxf(fd,       0.f), 33.f);
    float qd1 = fminf(fmaxf(fd + 1.f, 0.f), 33.f);
    float qh0 = fminf(fmaxf(fh,       0.f), 49.f);
    float qh1 = fminf(fmaxf(fh + 1.f, 0.f), 49.f);
    float qw0 = fminf(fmaxf(fw,       0.f), 49.f);
    float qw1 = fminf(fmaxf(fw + 1.f, 0.f), 49.f);
    float pcd = fminf(fmaxf(pdp, 0.f), 33.f);
    float pch = fminf(fmaxf(php, 0.f), 49.f);
    float pcw = fminf(fmaxf(pwp, 0.f), 49.f);

    float gd0 = 1.f + (qd0 - pcd), gd1 = 1.f - (qd1 - pcd);
    float gh0 = 1.f + (qh0 - pch), gh1 = 1.f - (qh1 - pch);
    float gw0 = 1.f + (qw0 - pcw), gw1 = 1.f - (qw1 - pcw);
    // pad-corner semantics: zero per-axis gain, clamp index to real range
    gd0 = (qd0 >= 1.f && qd0 <= 32.f) ? gd0 : 0.f;
    gd1 = (qd1 >= 1.f && qd1 <= 32.f) ? gd1 : 0.f;
    gh0 = (qh0 >= 1.f && qh0 <= 48.f) ? gh0 : 0.f;
    gh1 = (qh1 >= 1.f && qh1 <= 48.f) ? gh1 : 0.f;
    gw0 = (qw0 >= 1.f && qw0 <= 48.f) ? gw0 : 0.f;
    gw1 = (qw1 >= 1.f && qw1 <= 48.f) ? gw1 : 0.f;
    int zd0 = (int)fminf(fmaxf(qd0, 1.f), 32.f) - 1;
    int zd1 = (int)fminf(fmaxf(qd1, 1.f), 32.f) - 1;
    int zh0 = (int)fminf(fmaxf(qh0, 1.f), 48.f) - 1;
    int zh1 = (int)fminf(fmaxf(qh1, 1.f), 48.f) - 1;
    int zw0 = (int)fminf(fmaxf(qw0, 1.f), 48.f) - 1;
    int zw1 = (int)fminf(fmaxf(qw1, 1.f), 48.f) - 1;

    int bd0 = zd0 * 2304, bd1 = zd1 * 2304;
    int bh0 = zh0 * 48,   bh1 = zh1 * 48;
    float gdh00 = gd0 * gh0, gdh01 = gd0 * gh1;
    float gdh10 = gd1 * gh0, gdh11 = gd1 * gh1;

    tb.cw[0] = Xu[(size_t)(bd0 + bh0 + zw0) * 4 + kg];
    tb.cw[1] = Xu[(size_t)(bd0 + bh0 + zw1) * 4 + kg];
    tb.cw[2] = Xu[(size_t)(bd0 + bh1 + zw0) * 4 + kg];
    tb.cw[3] = Xu[(size_t)(bd0 + bh1 + zw1) * 4 + kg];
    tb.cw[4] = Xu[(size_t)(bd1 + bh0 + zw0) * 4 + kg];
    tb.cw[5] = Xu[(size_t)(bd1 + bh0 + zw1) * 4 + kg];
    tb.cw[6] = Xu[(size_t)(bd1 + bh1 + zw0) * 4 + kg];
    tb.cw[7] = Xu[(size_t)(bd1 + bh1 + zw1) * 4 + kg];
    tb.wb0   = Wu[(size_t)(n * 2 + 0) * 64 + lane];
    tb.wb1   = Wu[(size_t)(n * 2 + 1) * 64 + lane];

    tb.gg[0] = gdh00 * gw0;  tb.gg[1] = gdh00 * gw1;
    tb.gg[2] = gdh01 * gw0;  tb.gg[3] = gdh01 * gw1;
    tb.gg[4] = gdh10 * gw0;  tb.gg[5] = gdh10 * gw1;
    tb.gg[6] = gdh11 * gw0;  tb.gg[7] = gdh11 * gw1;
}

__device__ __forceinline__ void tap_consume(
        const Gath& tb, f32x4& acc0, f32x4& acc1)
{
    f32x2 xa0 = {0.f, 0.f}, xa1 = {0.f, 0.f};
    f32x2 xa2 = {0.f, 0.f}, xa3 = {0.f, 0.f};

    #pragma unroll
    for (int e = 0; e < 8; ++e) {
        uint4 cw = tb.cw[e];
        f32x2 g2 = {tb.gg[e], tb.gg[e]};
        f32x2 v0 = {bitsf(cw.x << 16), bitsf(cw.x & 0xFFFF0000u)};
        f32x2 v1 = {bitsf(cw.y << 16), bitsf(cw.y & 0xFFFF0000u)};
        f32x2 v2 = {bitsf(cw.z << 16), bitsf(cw.z & 0xFFFF0000u)};
        f32x2 v3 = {bitsf(cw.w << 16), bitsf(cw.w & 0xFFFF0000u)};
        asm("v_pk_fma_f32 %0, %1, %2, %0" : "+v"(xa0) : "v"(v0), "v"(g2));
        asm("v_pk_fma_f32 %0, %1, %2, %0" : "+v"(xa1) : "v"(v1), "v"(g2));
        asm("v_pk_fma_f32 %0, %1, %2, %0" : "+v"(xa2) : "v"(v2), "v"(g2));
        asm("v_pk_fma_f32 %0, %1, %2, %0" : "+v"(xa3) : "v"(v3), "v"(g2));
    }

    union { unsigned u[4]; short8 s; } av;
    asm("v_cvt_pk_bf16_f32 %0, %1, %2" : "=v"(av.u[0]) : "v"(xa0.x), "v"(xa0.y));
    asm("v_cvt_pk_bf16_f32 %0, %1, %2" : "=v"(av.u[1]) : "v"(xa1.x), "v"(xa1.y));
    asm("v_cvt_pk_bf16_f32 %0, %1, %2" : "=v"(av.u[2]) : "v"(xa2.x), "v"(xa2.y));
    asm("v_cvt_pk_bf16_f32 %0, %1, %2" : "=v"(av.u[3]) : "v"(xa3.x), "v"(xa3.y));

    union { uint4 u; short8 s; } b0, b1;
    b0.u = tb.wb0; b1.u = tb.wb1;
    acc0 = __builtin_amdgcn_mfma_f32_16x16x32_bf16(av.s, b0.s, acc0, 0, 0, 0);
    acc1 = __builtin_amdgcn_mfma_f32_16x16x32_bf16(av.s, b1.s, acc1, 0, 0, 0);
}

// ---------------- Fused kernel: offset conv (MFMA) -> LDS -> deform (MFMA)
// 2-wave blocks (32 pos). Plain C++ loads; sched_barrier(0) fences pin the
// 2-deep issue/consume pipeline so ~10 gathers stay in flight (compiler
// emits counted vmcnt for its own loads).
__global__ __launch_bounds__(128, 3) void fused_deform6(
        const unsigned short* __restrict__ xT,    // [SPATIAL][32] bf16
        const unsigned short* __restrict__ Bp2,
        const unsigned short* __restrict__ wpk,
        float* __restrict__ out)                  // [32][SPATIAL] f32
{
    __shared__ float offl[2][16][97];             // 12.4 KB

    const int tid  = threadIdx.x;
    const int lane = tid & 63, wv = tid >> 6;
    const int p0   = blockIdx.x * 32 + wv * 16;
    const int kg   = lane >> 4;
    const int row  = lane & 15;
    const int pos  = p0 + row;
    const int w = pos % WW, h = (pos / WW) % HH, d = pos / (WW * HH);

    const uint4* Xu = (const uint4*)xT;
    const uint4* Bu = (const uint4*)Bp2;
    const uint4* Wu = (const uint4*)wpk;

    // ---------------- phase 1: offset conv, 2-deep pipelined ----------------
    f32x4 cacc[6];
    #pragma unroll
    for (int j = 0; j < 6; ++j) cacc[j] = (f32x4){0.f, 0.f, 0.f, 0.f};

    {
        ConvT cA, cB;
        conv_issue(cA, Xu, Bu, 0, pos, d, h, w, kg, lane);
        SB0();
        #pragma unroll 1
        for (int n = 0; n < 26; n += 2) {
            conv_issue(cB, Xu, Bu, n + 1, pos, d, h, w, kg, lane);
            SB0();
            conv_consume(cA, cacc);
            conv_issue(cA, Xu, Bu, n + 2, pos, d, h, w, kg, lane);
            SB0();
            conv_consume(cB, cacc);
        }
        conv_consume(cA, cacc);                   // tap 26
    }

    // ---------------- phase 2: D-frags -> wave-local LDS ----------------
    #pragma unroll
    for (int j = 0; j < 6; ++j) {
        #pragma unroll
        for (int r = 0; r < 4; ++r)
            offl[wv][kg * 4 + r][j * 16 + row] = cacc[j][r];
    }
    __syncthreads();

    // ---------------- phase 3: pipelined deform gather + einsum ----------------
    const float* ol = &offl[wv][row][0];

    f32x4 acc0 = {0.f, 0.f, 0.f, 0.f};
    f32x4 acc1 = {0.f, 0.f, 0.f, 0.f};

    {
        Gath gA, gB;
        float odA = ol[0], ohA = ol[27], owA = ol[54];
        tap_issue(gA, Xu, Wu, odA, ohA, owA, 0, d, h, w, kg, lane);
        SB0();
        float odB = ol[1], ohB = ol[28], owB = ol[55];

        #pragma unroll 1
        for (int n = 0; n < 26; n += 2) {
            tap_issue(gB, Xu, Wu, odB, ohB, owB, n + 1, d, h, w, kg, lane);
            SB0();
            odA = ol[n + 2]; ohA = ol[27 + n + 2]; owA = ol[54 + n + 2];
            tap_consume(gA, acc0, acc1);
            tap_issue(gA, Xu, Wu, odA, ohA, owA, n + 2, d, h, w, kg, lane);
            SB0();
            int nb = (n + 3 < 27) ? n + 3 : 26;
            odB = ol[nb]; ohB = ol[27 + nb]; owB = ol[54 + nb];
            tap_consume(gB, acc0, acc1);
        }
        tap_consume(gA, acc0, acc1);              // tap 26
    }

    // D layout: col = lane&15 -> oc, row = kg*4+reg -> pos
    const int pb = p0 + kg * 4;
    *(f32x4*)&out[(size_t)row        * SPATIAL + pb] = acc0;
    *(f32x4*)&out[(size_t)(16 + row) * SPATIAL + pb] = acc1;
}

// ----------------------------------------------------------------------------
extern "C" void kernel_launch(void* const* d_in, const int* in_sizes, int n_in,
                              void* d_out, int out_size, void* d_ws, size_t ws_size,
                              hipStream_t stream)
{
    const float* x     = (const float*)d_in[0];
    const float* w_off = (const float*)d_in[1];
    const float* w_def = (const float*)d_in[2];
    float* out = (float*)d_out;

    unsigned short* Bp2 = (unsigned short*)((char*)d_ws);
    unsigned short* wpk = (unsigned short*)((char*)d_ws + OFF_WPK);
    unsigned short* xT  = (unsigned short*)((char*)d_ws + OFF_XT);

    wprep2_kernel<<<(BP2_ELEMS + 255) / 256, 256, 0, stream>>>(w_off, Bp2);
    wdefprep_kernel<<<(WPK_ELEMS + 255) / 256, 256, 0, stream>>>(w_def, wpk);
    xtrans_kernel<<<SPATIAL / 64, 256, 0, stream>>>(x, xT);
    fused_deform6<<<SPATIAL / 32, 128, 0, stream>>>(xT, Bp2, wpk, out);
}